// Round 5
// baseline (276.234 us; speedup 1.0000x reference)
//
#include <hip/hip_runtime.h>
#include <hip/hip_bf16.h>
#include <math.h>

#define BATCH   8192
#define NFIELD  24
#define FAC     16
#define PAIRS   276
#define NSETS   24             // 23 real 12-pair sets + 1 idle set
#define SETLEN  12
#define NSB     (BATCH / 32)   // 256 batch slabs of 32 rows

typedef __attribute__((ext_vector_type(8))) __bf16 bf16x8;
typedef __attribute__((ext_vector_type(4))) float f32x4;

// ---- workspace layout (bytes) ----
// xvT:   [128][24][2][64][8] bf16 = 6,291,456
// combo: [276 + 2 pad][4608]      = 1,281,024 (+pad)
// partial:[24][8192] f32          =   786,432
// wval:  [24][8192] f32           =   786,432
// consts: [1] f32
#define XVT_OFF   0
#define COMBO_OFF 6291456
#define PART_OFF  (COMBO_OFF + 1285632)
#define WVAL_OFF  (PART_OFF + 786432)
#define CONST_OFF (WVAL_OFF + 786432)

// Fused prep: blocks [0,768) gather v->xvT (+ w linear term -> wval);
// blocks [768,837) repack weights.
__global__ void prep_all(const int* __restrict__ inputs,
                         const float* __restrict__ v,
                         const float* __restrict__ w,
                         const float* __restrict__ W1,
                         const float* __restrict__ W2,
                         const float* __restrict__ b1,
                         const float* __restrict__ b2,
                         const float* __restrict__ bsc,
                         __hip_bfloat16* __restrict__ xvT,
                         char* __restrict__ combo,
                         float* __restrict__ wval,
                         float* __restrict__ consts) {
    __shared__ float red[256];
    int blk = blockIdx.x;
    if (blk < 768) {
        int t = blk * 256 + threadIdx.x;          // < 196608
        int field = t >> 13;
        int b = t & 8191;
        int idx = inputs[b * NFIELD + field];
        const float4* src = (const float4*)(v + (long)idx * FAC);
        union { __hip_bfloat16 h[16]; uint4 u[2]; } tmp;
        float4 a0 = src[0], a1 = src[1], a2 = src[2], a3 = src[3];
        tmp.h[0]  = __float2bfloat16(a0.x); tmp.h[1]  = __float2bfloat16(a0.y);
        tmp.h[2]  = __float2bfloat16(a0.z); tmp.h[3]  = __float2bfloat16(a0.w);
        tmp.h[4]  = __float2bfloat16(a1.x); tmp.h[5]  = __float2bfloat16(a1.y);
        tmp.h[6]  = __float2bfloat16(a1.z); tmp.h[7]  = __float2bfloat16(a1.w);
        tmp.h[8]  = __float2bfloat16(a2.x); tmp.h[9]  = __float2bfloat16(a2.y);
        tmp.h[10] = __float2bfloat16(a2.z); tmp.h[11] = __float2bfloat16(a2.w);
        tmp.h[12] = __float2bfloat16(a3.x); tmp.h[13] = __float2bfloat16(a3.y);
        tmp.h[14] = __float2bfloat16(a3.z); tmp.h[15] = __float2bfloat16(a3.w);
        int bb = b >> 6, row = b & 63;
        __hip_bfloat16* base = xvT + (long)bb * 24576 + field * 1024 + row * 8;
        *(uint4*)base         = tmp.u[0];
        *(uint4*)(base + 512) = tmp.u[1];
        // linear-term gather, coalesced write (read by finalize)
        wval[field * BATCH + b] = w[idx];
    } else {
        int wb = blk - 768;                        // 0..68
        int t = wb * 256 + threadIdx.x;            // < 17664
        int p = t >> 6;
        int L = t & 63;
        int q = L >> 4, c = L & 15;
        char* base = combo + (long)p * 4608;
        union { __hip_bfloat16 h[8]; uint4 u; } buf;
#pragma unroll
        for (int tt = 0; tt < 4; ++tt) {
#pragma unroll
            for (int jj = 0; jj < 8; ++jj)
                buf.h[jj] = __float2bfloat16(W1[p * 2048 + (q * 8 + jj) * 64 + tt * 16 + c]);
            *(uint4*)(base + 512 + tt * 1024 + L * 16) = buf.u;
        }
        if (L < 16) {
            float4 bv = {b1[p * 64 + L], b1[p * 64 + 16 + L], b1[p * 64 + 32 + L], b1[p * 64 + 48 + L]};
            *(float4*)(base + L * 16) = bv;
            float4 wv = {W2[p * 64 + L], W2[p * 64 + 16 + L], W2[p * 64 + 32 + L], W2[p * 64 + 48 + L]};
            *(float4*)(base + 256 + L * 16) = wv;
        }
        if (wb == 1) {   // zero the 2 pad pairs (depth-2 tail prefetch reads them)
            uint4 z = {0, 0, 0, 0};
            for (int k = threadIdx.x; k < 576; k += 256)
                *(uint4*)(combo + (long)PAIRS * 4608 + k * 16) = z;
        }
        if (wb == 0) {
            float s = 0.f;
            for (int k = threadIdx.x; k < PAIRS; k += 256) s += b2[k];
            red[threadIdx.x] = s;
            __syncthreads();
            for (int off = 128; off > 0; off >>= 1) {
                if (threadIdx.x < off) red[threadIdx.x] += red[threadIdx.x + off];
                __syncthreads();
            }
            if (threadIdx.x == 0) consts[0] = red[0] + bsc[0];
        }
    }
}

// One pair's weight package in registers. Bias pre-broadcast into persistent
// MFMA C-operands (D!=C, so cb survives and is reused across both row-tiles).
struct Pkg {
    f32x4 cb0, cb1, cb2, cb3;
    float4 mw;
    bf16x8 f0, f1, f2, f3;
};

__device__ __forceinline__ Pkg load_pkg(const char* p, int mcol, int l16) {
    Pkg k;
    float4 tb = *(const float4*)(p + mcol);
    k.cb0 = (f32x4){tb.x, tb.x, tb.x, tb.x};
    k.cb1 = (f32x4){tb.y, tb.y, tb.y, tb.y};
    k.cb2 = (f32x4){tb.z, tb.z, tb.z, tb.z};
    k.cb3 = (f32x4){tb.w, tb.w, tb.w, tb.w};
    k.mw = *(const float4*)(p + 256 + mcol);
    k.f0 = *(const bf16x8*)(p + 512  + l16);
    k.f1 = *(const bf16x8*)(p + 1536 + l16);
    k.f2 = *(const bf16x8*)(p + 2560 + l16);
    k.f3 = *(const bf16x8*)(p + 3584 + l16);
    return k;
}

// Apply one package to both row-tiles. Packed-f32 epilogue (v_pk_max/v_pk_fma).
#define PKGCOMP(P)                                                            \
    {                                                                         \
        int fso = ((quad < 2) ? i : j) * 544;                                 \
        const f32x4 z4 = {0.f, 0.f, 0.f, 0.f};                                \
        _Pragma("unroll")                                                     \
        for (int t = 0; t < 2; ++t) {                                         \
            bf16x8 af = *(const bf16x8*)(xv_s + fso + abase + t * 128);       \
            f32x4 c0 = __builtin_amdgcn_mfma_f32_16x16x32_bf16(af, P.f0, P.cb0, 0, 0, 0); \
            f32x4 c1 = __builtin_amdgcn_mfma_f32_16x16x32_bf16(af, P.f1, P.cb1, 0, 0, 0); \
            f32x4 c2 = __builtin_amdgcn_mfma_f32_16x16x32_bf16(af, P.f2, P.cb2, 0, 0, 0); \
            f32x4 c3 = __builtin_amdgcn_mfma_f32_16x16x32_bf16(af, P.f3, P.cb3, 0, 0, 0); \
            acc[t] = acc[t] + __builtin_elementwise_max(c0, z4) * P.mw.x;     \
            acc[t] = acc[t] + __builtin_elementwise_max(c1, z4) * P.mw.y;     \
            acc[t] = acc[t] + __builtin_elementwise_max(c2, z4) * P.mw.z;     \
            acc[t] = acc[t] + __builtin_elementwise_max(c3, z4) * P.mw.w;     \
        }                                                                     \
        ++j;                                                                  \
        if (j == NFIELD) { ++i; j = i + 1; }                                  \
    }

// 256-thread blocks over 32-row slabs: LDS 25.5KB -> 6 blocks/CU = 24
// waves/CU (75% occupancy, was 37.5% at 64-row slabs/51KB). Grid 1536 =
// 6 x 256 CUs exactly. Each wave owns one 12-pair set; barrier-free K-loop,
// depth-2 register prefetch issued before the stage DMA + barrier.
// LDS layout: [field][half][row32][8] bf16 with +32 elem (64B) pad per
// 512-elem (1024B) group => stage swizzle dst = ch*16 + (ch>>6)*64 is
// wave-linear (global_load_lds HW requirement), A-frag addr = f*544 +
// (quad&1)*256 + col*8 + t*128.
__global__ __launch_bounds__(256, 6) void ffm_main(
        const __hip_bfloat16* __restrict__ xvT,
        const char* __restrict__ combo,
        float* __restrict__ partial) {
    __shared__ __align__(16) __hip_bfloat16 xv_s[13056];  // 25.5 KB

    int tid  = threadIdx.x;
    int sb   = blockIdx.x & (NSB - 1);   // 32-row slab id, 0..255
    int pg   = blockIdx.x >> 8;          // 0..5
    int lane = tid & 63;
    int wave = tid >> 6;
    int col  = lane & 15;
    int quad = lane >> 4;

    int bb64 = sb >> 1;                  // source 64-row block in xvT
    int h    = sb & 1;                   // which half (rows 32h..32h+31)

    const int abase = (quad & 1) * 256 + col * 8;   // + t*128 per row-tile
    const int mcol  = col * 16;
    const int l16   = lane * 16;

    // ---- issue weight-package prefetch first (overlaps the stage DMA) ----
    int setid = pg * 4 + wave;           // 0..23; set 23 idle (writes zeros)
    int i = 0, j = 1;
    const char* wp = combo;
    Pkg A, B;
    bool active = (setid < 23);
    if (active) {
        int p0 = setid * SETLEN;
        int rem = p0;
        while (rem >= NFIELD - 1 - i) { rem -= NFIELD - 1 - i; ++i; }
        j = i + 1 + rem;
        wp = combo + (long)p0 * 4608;
        A = load_pkg(wp, mcol, l16);
        B = load_pkg(wp + 4608, mcol, l16);
    }

    // ---- stage 24KB half-slab: 1536 16B chunks ----
    // chunk ch: seg = ch>>5 (f = seg>>1, hf = seg&1), off = ch&31.
    // src = f*2048 + hf*1024 + h*512 + off*16 (per-lane address is fine);
    // dst = ch*16 + (ch>>6)*64 (wave-linear: ch0 = it*256+wave*64).
    {
        const char* srcb = (const char*)(xvT + (long)bb64 * 24576);
        int hoff = h * 512;
#if __has_builtin(__builtin_amdgcn_global_load_lds)
#pragma unroll
        for (int it = 0; it < 6; ++it) {
            int ch0 = it * 256 + wave * 64;                   // wave-uniform
            int ch  = ch0 + lane;
            char* ldst = (char*)xv_s + ch0 * 16 + (ch0 >> 6) * 64;
            int f  = ch >> 6;
            int hf = (ch >> 5) & 1;
            int off = ch & 31;
            const char* g = srcb + f * 2048 + hf * 1024 + hoff + off * 16;
            __builtin_amdgcn_global_load_lds(
                (const __attribute__((address_space(1))) unsigned int*)g,
                (__attribute__((address_space(3))) unsigned int*)ldst,
                16, 0, 0);
        }
#else
#pragma unroll
        for (int it = 0; it < 6; ++it) {
            int ch = it * 256 + tid;
            int f  = ch >> 6;
            int hf = (ch >> 5) & 1;
            int off = ch & 31;
            uint4 val = *(const uint4*)(srcb + f * 2048 + hf * 1024 + hoff + off * 16);
            *(uint4*)((char*)xv_s + ch * 16 + (ch >> 6) * 64) = val;
        }
#endif
    }
    __syncthreads();   // compiler drains vmcnt (incl. global_load_lds) here

    f32x4 acc[2];
    acc[0] = (f32x4){0.f, 0.f, 0.f, 0.f};
    acc[1] = (f32x4){0.f, 0.f, 0.f, 0.f};

    if (active) {
#pragma unroll 2
        for (int k = 0; k < SETLEN; k += 2) {
            PKGCOMP(A)
            A = load_pkg(wp + 2 * 4608, mcol, l16);   // used 2 iters later
            PKGCOMP(B)
            B = load_pkg(wp + 3 * 4608, mcol, l16);
            wp += 2 * 4608;
        }
    }

    // reduce each acc component over the 16 column-lanes within its quad group
#pragma unroll
    for (int m = 1; m < 16; m <<= 1) {
#pragma unroll
        for (int t = 0; t < 2; ++t) {
#pragma unroll
            for (int r = 0; r < 4; ++r) acc[t][r] += __shfl_xor(acc[t][r], m, 64);
        }
    }
    if (col == 0) {
#pragma unroll
        for (int t = 0; t < 2; ++t) {
            f32x4 o = acc[t];
            *(f32x4*)&partial[setid * BATCH + sb * 32 + t * 16 + quad * 4] = o;
        }
    }
}

// Per-row finalize. All 48 loads are coalesced across threads (stride-BATCH
// columns) and mutually independent, so they overlap into ~2 memory round trips.
__global__ void finalize(const float* __restrict__ wval,
                         const float* __restrict__ consts,
                         const float* __restrict__ partial,
                         float* __restrict__ out) {
    int b = blockIdx.x * 256 + threadIdx.x;   // < 8192
    float s = consts[0];
#pragma unroll
    for (int f = 0; f < NFIELD; ++f) s += wval[f * BATCH + b];
#pragma unroll
    for (int g = 0; g < NSETS; ++g) s += partial[g * BATCH + b];
    out[b] = 1.0f / (1.0f + expf(-s));
}

extern "C" void kernel_launch(void* const* d_in, const int* in_sizes, int n_in,
                              void* d_out, int out_size, void* d_ws, size_t ws_size,
                              hipStream_t stream) {
    const int*   inputs = (const int*)d_in[0];
    const float* w      = (const float*)d_in[1];
    const float* v      = (const float*)d_in[2];
    const float* bsc    = (const float*)d_in[3];
    const float* W1     = (const float*)d_in[4];
    const float* b1     = (const float*)d_in[5];
    const float* W2     = (const float*)d_in[6];
    const float* b2     = (const float*)d_in[7];
    float* out = (float*)d_out;

    char* ws = (char*)d_ws;
    __hip_bfloat16* xvT = (__hip_bfloat16*)(ws + XVT_OFF);
    char*  combo   = ws + COMBO_OFF;
    float* partial = (float*)(ws + PART_OFF);
    float* wval    = (float*)(ws + WVAL_OFF);
    float* consts  = (float*)(ws + CONST_OFF);

    prep_all<<<768 + 69, 256, 0, stream>>>(inputs, v, w, W1, W2, b1, b2, bsc,
                                           xvT, combo, wval, consts);
    ffm_main<<<NSB * 6, 256, 0, stream>>>(xvT, combo, partial);
    finalize<<<BATCH / 256, 256, 0, stream>>>(wval, consts, partial, out);
}

// Round 6
// 137.728 us; speedup vs baseline: 2.0057x; 2.0057x over previous
//
#include <hip/hip_runtime.h>
#include <hip/hip_bf16.h>
#include <math.h>

#define BATCH   8192
#define NFIELD  24
#define FAC     16
#define PAIRS   276
#define NSETS   24             // 23 real 12-pair sets + 1 idle set
#define SETLEN  12
#define NSB     (BATCH / 32)   // 256 batch slabs of 32 rows

typedef __attribute__((ext_vector_type(8))) __bf16 bf16x8;
typedef __attribute__((ext_vector_type(4))) float f32x4;

// ---- workspace layout (bytes) ----
// xvT:   [128][24][2][64][8] bf16 = 6,291,456
// combo: [276 + 2 pad][4608]      = 1,281,024 (+pad)
// partial:[24][8192] f32          =   786,432
// wval:  [24][8192] f32           =   786,432
// consts: [1] f32
#define XVT_OFF   0
#define COMBO_OFF 6291456
#define PART_OFF  (COMBO_OFF + 1285632)
#define WVAL_OFF  (PART_OFF + 786432)
#define CONST_OFF (WVAL_OFF + 786432)

// Fused prep: blocks [0,768) gather v->xvT (+ w linear term -> wval);
// blocks [768,837) repack weights.
__global__ void prep_all(const int* __restrict__ inputs,
                         const float* __restrict__ v,
                         const float* __restrict__ w,
                         const float* __restrict__ W1,
                         const float* __restrict__ W2,
                         const float* __restrict__ b1,
                         const float* __restrict__ b2,
                         const float* __restrict__ bsc,
                         __hip_bfloat16* __restrict__ xvT,
                         char* __restrict__ combo,
                         float* __restrict__ wval,
                         float* __restrict__ consts) {
    __shared__ float red[256];
    int blk = blockIdx.x;
    if (blk < 768) {
        int t = blk * 256 + threadIdx.x;          // < 196608
        int field = t >> 13;
        int b = t & 8191;
        int idx = inputs[b * NFIELD + field];
        const float4* src = (const float4*)(v + (long)idx * FAC);
        union { __hip_bfloat16 h[16]; uint4 u[2]; } tmp;
        float4 a0 = src[0], a1 = src[1], a2 = src[2], a3 = src[3];
        tmp.h[0]  = __float2bfloat16(a0.x); tmp.h[1]  = __float2bfloat16(a0.y);
        tmp.h[2]  = __float2bfloat16(a0.z); tmp.h[3]  = __float2bfloat16(a0.w);
        tmp.h[4]  = __float2bfloat16(a1.x); tmp.h[5]  = __float2bfloat16(a1.y);
        tmp.h[6]  = __float2bfloat16(a1.z); tmp.h[7]  = __float2bfloat16(a1.w);
        tmp.h[8]  = __float2bfloat16(a2.x); tmp.h[9]  = __float2bfloat16(a2.y);
        tmp.h[10] = __float2bfloat16(a2.z); tmp.h[11] = __float2bfloat16(a2.w);
        tmp.h[12] = __float2bfloat16(a3.x); tmp.h[13] = __float2bfloat16(a3.y);
        tmp.h[14] = __float2bfloat16(a3.z); tmp.h[15] = __float2bfloat16(a3.w);
        int bb = b >> 6, row = b & 63;
        __hip_bfloat16* base = xvT + (long)bb * 24576 + field * 1024 + row * 8;
        *(uint4*)base         = tmp.u[0];
        *(uint4*)(base + 512) = tmp.u[1];
        // linear-term gather, coalesced write (read by finalize)
        wval[field * BATCH + b] = w[idx];
    } else {
        int wb = blk - 768;                        // 0..68
        int t = wb * 256 + threadIdx.x;            // < 17664
        int p = t >> 6;
        int L = t & 63;
        int q = L >> 4, c = L & 15;
        char* base = combo + (long)p * 4608;
        union { __hip_bfloat16 h[8]; uint4 u; } buf;
#pragma unroll
        for (int tt = 0; tt < 4; ++tt) {
#pragma unroll
            for (int jj = 0; jj < 8; ++jj)
                buf.h[jj] = __float2bfloat16(W1[p * 2048 + (q * 8 + jj) * 64 + tt * 16 + c]);
            *(uint4*)(base + 512 + tt * 1024 + L * 16) = buf.u;
        }
        if (L < 16) {
            float4 bv = {b1[p * 64 + L], b1[p * 64 + 16 + L], b1[p * 64 + 32 + L], b1[p * 64 + 48 + L]};
            *(float4*)(base + L * 16) = bv;
            float4 wv = {W2[p * 64 + L], W2[p * 64 + 16 + L], W2[p * 64 + 32 + L], W2[p * 64 + 48 + L]};
            *(float4*)(base + 256 + L * 16) = wv;
        }
        if (wb == 1) {   // zero the 2 pad pairs (depth-2 tail prefetch reads them)
            uint4 z = {0, 0, 0, 0};
            for (int k = threadIdx.x; k < 576; k += 256)
                *(uint4*)(combo + (long)PAIRS * 4608 + k * 16) = z;
        }
        if (wb == 0) {
            float s = 0.f;
            for (int k = threadIdx.x; k < PAIRS; k += 256) s += b2[k];
            red[threadIdx.x] = s;
            __syncthreads();
            for (int off = 128; off > 0; off >>= 1) {
                if (threadIdx.x < off) red[threadIdx.x] += red[threadIdx.x + off];
                __syncthreads();
            }
            if (threadIdx.x == 0) consts[0] = red[0] + bsc[0];
        }
    }
}

// One pair's weight package in registers. Bias pre-broadcast into persistent
// MFMA C-operands (D!=C, so cb survives and is reused across both row-tiles).
struct Pkg {
    f32x4 cb0, cb1, cb2, cb3;
    float4 mw;
    bf16x8 f0, f1, f2, f3;
};

__device__ __forceinline__ Pkg load_pkg(const char* p, int mcol, int l16) {
    Pkg k;
    float4 tb = *(const float4*)(p + mcol);
    k.cb0 = (f32x4){tb.x, tb.x, tb.x, tb.x};
    k.cb1 = (f32x4){tb.y, tb.y, tb.y, tb.y};
    k.cb2 = (f32x4){tb.z, tb.z, tb.z, tb.z};
    k.cb3 = (f32x4){tb.w, tb.w, tb.w, tb.w};
    k.mw = *(const float4*)(p + 256 + mcol);
    k.f0 = *(const bf16x8*)(p + 512  + l16);
    k.f1 = *(const bf16x8*)(p + 1536 + l16);
    k.f2 = *(const bf16x8*)(p + 2560 + l16);
    k.f3 = *(const bf16x8*)(p + 3584 + l16);
    return k;
}

// Apply one package to both row-tiles. Packed-f32 epilogue (v_pk_max/v_pk_fma).
#define PKGCOMP(P)                                                            \
    {                                                                         \
        int fso = ((quad < 2) ? i : j) * 544;                                 \
        const f32x4 z4 = {0.f, 0.f, 0.f, 0.f};                                \
        _Pragma("unroll")                                                     \
        for (int t = 0; t < 2; ++t) {                                         \
            bf16x8 af = *(const bf16x8*)(xv_s + fso + abase + t * 128);       \
            f32x4 c0 = __builtin_amdgcn_mfma_f32_16x16x32_bf16(af, P.f0, P.cb0, 0, 0, 0); \
            f32x4 c1 = __builtin_amdgcn_mfma_f32_16x16x32_bf16(af, P.f1, P.cb1, 0, 0, 0); \
            f32x4 c2 = __builtin_amdgcn_mfma_f32_16x16x32_bf16(af, P.f2, P.cb2, 0, 0, 0); \
            f32x4 c3 = __builtin_amdgcn_mfma_f32_16x16x32_bf16(af, P.f3, P.cb3, 0, 0, 0); \
            acc[t] = acc[t] + __builtin_elementwise_max(c0, z4) * P.mw.x;     \
            acc[t] = acc[t] + __builtin_elementwise_max(c1, z4) * P.mw.y;     \
            acc[t] = acc[t] + __builtin_elementwise_max(c2, z4) * P.mw.z;     \
            acc[t] = acc[t] + __builtin_elementwise_max(c3, z4) * P.mw.w;     \
        }                                                                     \
        ++j;                                                                  \
        if (j == NFIELD) { ++i; j = i + 1; }                                  \
    }

// 256-thread blocks over 32-row slabs. LDS 25.5KB; __launch_bounds__(256,4):
// VGPR budget 512/4 = 128 >= natural ~80 (NO spill — round-5 lesson: the
// (256,6) budget of 85 spilled both Pkgs to scratch, 475MB of HBM writes).
// 4 blocks/CU = 16 waves/CU. Each wave owns one 12-pair set; barrier-free
// K-loop, depth-2 register prefetch issued before the stage DMA + barrier.
// LDS layout: [field][half][row32][8] bf16, +64B pad per field (stride 1088B);
// stage swizzle dst = ch*16 + (ch>>6)*64 is wave-linear (global_load_lds HW
// requirement); A-frag elem addr = f*544 + (quad&1)*256 + col*8 + t*128.
__global__ __launch_bounds__(256, 4) void ffm_main(
        const __hip_bfloat16* __restrict__ xvT,
        const char* __restrict__ combo,
        float* __restrict__ partial) {
    __shared__ __align__(16) __hip_bfloat16 xv_s[13056];  // 25.5 KB

    int tid  = threadIdx.x;
    int sb   = blockIdx.x & (NSB - 1);   // 32-row slab id, 0..255
    int pg   = blockIdx.x >> 8;          // 0..5
    int lane = tid & 63;
    int wave = tid >> 6;
    int col  = lane & 15;
    int quad = lane >> 4;

    int bb64 = sb >> 1;                  // source 64-row block in xvT
    int h    = sb & 1;                   // which half (rows 32h..32h+31)

    const int abase = (quad & 1) * 256 + col * 8;   // + t*128 per row-tile
    const int mcol  = col * 16;
    const int l16   = lane * 16;

    // ---- issue weight-package prefetch first (overlaps the stage DMA) ----
    int setid = pg * 4 + wave;           // 0..23; set 23 idle (writes zeros)
    int i = 0, j = 1;
    const char* wp = combo;
    Pkg A, B;
    bool active = (setid < 23);
    if (active) {
        int p0 = setid * SETLEN;
        int rem = p0;
        while (rem >= NFIELD - 1 - i) { rem -= NFIELD - 1 - i; ++i; }
        j = i + 1 + rem;
        wp = combo + (long)p0 * 4608;
        A = load_pkg(wp, mcol, l16);
        B = load_pkg(wp + 4608, mcol, l16);
    }

    // ---- stage 24KB half-slab: 1536 16B chunks ----
    // chunk ch: f = ch>>6 (wave-uniform), hf = (ch>>5)&1, off = ch&31.
    // src = f*2048 + hf*1024 + h*512 + off*16 (per-lane address ok);
    // dst = ch*16 + (ch>>6)*64 (wave-linear: ch0 = it*256+wave*64).
    {
        const char* srcb = (const char*)(xvT + (long)bb64 * 24576);
        int hoff = h * 512;
#if __has_builtin(__builtin_amdgcn_global_load_lds)
#pragma unroll
        for (int it = 0; it < 6; ++it) {
            int ch0 = it * 256 + wave * 64;                   // wave-uniform
            int ch  = ch0 + lane;
            char* ldst = (char*)xv_s + ch0 * 16 + (ch0 >> 6) * 64;
            int f  = ch >> 6;
            int hf = (ch >> 5) & 1;
            int off = ch & 31;
            const char* g = srcb + f * 2048 + hf * 1024 + hoff + off * 16;
            __builtin_amdgcn_global_load_lds(
                (const __attribute__((address_space(1))) unsigned int*)g,
                (__attribute__((address_space(3))) unsigned int*)ldst,
                16, 0, 0);
        }
#else
#pragma unroll
        for (int it = 0; it < 6; ++it) {
            int ch = it * 256 + tid;
            int f  = ch >> 6;
            int hf = (ch >> 5) & 1;
            int off = ch & 31;
            uint4 val = *(const uint4*)(srcb + f * 2048 + hf * 1024 + hoff + off * 16);
            *(uint4*)((char*)xv_s + ch * 16 + (ch >> 6) * 64) = val;
        }
#endif
    }
    __syncthreads();   // compiler drains vmcnt (incl. global_load_lds) here

    f32x4 acc[2];
    acc[0] = (f32x4){0.f, 0.f, 0.f, 0.f};
    acc[1] = (f32x4){0.f, 0.f, 0.f, 0.f};

    if (active) {
#pragma unroll 2
        for (int k = 0; k < SETLEN; k += 2) {
            PKGCOMP(A)
            A = load_pkg(wp + 2 * 4608, mcol, l16);   // used 2 iters later
            PKGCOMP(B)
            B = load_pkg(wp + 3 * 4608, mcol, l16);
            wp += 2 * 4608;
        }
    }

    // reduce each acc component over the 16 column-lanes within its quad group
#pragma unroll
    for (int m = 1; m < 16; m <<= 1) {
#pragma unroll
        for (int t = 0; t < 2; ++t) {
#pragma unroll
            for (int r = 0; r < 4; ++r) acc[t][r] += __shfl_xor(acc[t][r], m, 64);
        }
    }
    if (col == 0) {
#pragma unroll
        for (int t = 0; t < 2; ++t) {
            f32x4 o = acc[t];
            *(f32x4*)&partial[setid * BATCH + sb * 32 + t * 16 + quad * 4] = o;
        }
    }
}

// Per-row finalize. All 48 loads are coalesced across threads (stride-BATCH
// columns) and mutually independent, so they overlap into ~2 memory round trips.
__global__ void finalize(const float* __restrict__ wval,
                         const float* __restrict__ consts,
                         const float* __restrict__ partial,
                         float* __restrict__ out) {
    int b = blockIdx.x * 256 + threadIdx.x;   // < 8192
    float s = consts[0];
#pragma unroll
    for (int f = 0; f < NFIELD; ++f) s += wval[f * BATCH + b];
#pragma unroll
    for (int g = 0; g < NSETS; ++g) s += partial[g * BATCH + b];
    out[b] = 1.0f / (1.0f + expf(-s));
}

extern "C" void kernel_launch(void* const* d_in, const int* in_sizes, int n_in,
                              void* d_out, int out_size, void* d_ws, size_t ws_size,
                              hipStream_t stream) {
    const int*   inputs = (const int*)d_in[0];
    const float* w      = (const float*)d_in[1];
    const float* v      = (const float*)d_in[2];
    const float* bsc    = (const float*)d_in[3];
    const float* W1     = (const float*)d_in[4];
    const float* b1     = (const float*)d_in[5];
    const float* W2     = (const float*)d_in[6];
    const float* b2     = (const float*)d_in[7];
    float* out = (float*)d_out;

    char* ws = (char*)d_ws;
    __hip_bfloat16* xvT = (__hip_bfloat16*)(ws + XVT_OFF);
    char*  combo   = ws + COMBO_OFF;
    float* partial = (float*)(ws + PART_OFF);
    float* wval    = (float*)(ws + WVAL_OFF);
    float* consts  = (float*)(ws + CONST_OFF);

    prep_all<<<768 + 69, 256, 0, stream>>>(inputs, v, w, W1, W2, b1, b2, bsc,
                                           xvT, combo, wval, consts);
    ffm_main<<<NSB * 6, 256, 0, stream>>>(xvT, combo, partial);
    finalize<<<BATCH / 256, 256, 0, stream>>>(wval, consts, partial, out);
}